// Round 1
// baseline (17101.596 us; speedup 1.0000x reference)
//
#include <hip/hip_runtime.h>
#include <cstdint>
#include <cstddef>

// ---------------- numerics matched to XLA ----------------

__device__ __forceinline__ float keepf(float v){ asm volatile("" : "+v"(v)); return v; }

// XLA elemental_ir_emitter EmitTanh f32 (Eigen generic_fast_tanh_float + 0.0004 cutoff)
__device__ __forceinline__ float xtanh(float x){
  float ax = fabsf(x);
  float xc = fminf(fmaxf(x, -7.90531110763549805f), 7.90531110763549805f);
  float x2 = xc * xc;
  float np = -2.76076847742355e-16f;
  np = fmaf(np, x2, 2.00018790482477e-13f);
  np = fmaf(np, x2, -8.60467152213735e-11f);
  np = fmaf(np, x2, 5.12229709037114e-08f);
  np = fmaf(np, x2, 1.48572235717979e-05f);
  np = fmaf(np, x2, 6.37261928875436e-04f);
  np = fmaf(np, x2, 4.89352455891786e-03f);
  float num = xc * np;
  float dp = 1.19825839466702e-06f;
  dp = fmaf(dp, x2, 1.18534705686654e-04f);
  dp = fmaf(dp, x2, 2.26843463243900e-03f);
  dp = fmaf(dp, x2, 4.89352518554385e-03f);
  float r = num / dp;
  return (ax < 0.0004f) ? x : r;
}

// XLA logistic expander (modern): 1 / (1 + exp(-x))
__device__ __forceinline__ float xsig(float x){ return 1.0f / (1.0f + expf(-x)); }

// ---------------- Threefry-2x32 (JAX) ----------------
__device__ __forceinline__ void tf2x32(uint32_t k0, uint32_t k1, uint32_t x0, uint32_t x1,
                                       uint32_t& o0, uint32_t& o1){
  const uint32_t ks2 = k0 ^ k1 ^ 0x1BD11BDAu;
  x0 += k0; x1 += k1;
#define RR(r) { x0 += x1; x1 = (x1<<(r))|(x1>>(32-(r))); x1 ^= x0; }
  RR(13) RR(15) RR(26) RR(6)  x0 += k1;  x1 += ks2 + 1u;
  RR(17) RR(29) RR(16) RR(24) x0 += ks2; x1 += k0 + 2u;
  RR(13) RR(15) RR(26) RR(6)  x0 += k0;  x1 += k1 + 3u;
  RR(17) RR(29) RR(16) RR(24) x0 += k1;  x1 += ks2 + 4u;
  RR(13) RR(15) RR(26) RR(6)  x0 += ks2; x1 += k0 + 5u;
#undef RR
  o0 = x0; o1 = x1;
}

// partitionable random_bits(32): counter (hi=0, lo=ctr), bits = out0 ^ out1
__device__ __forceinline__ float gumbel_from(uint32_t k0, uint32_t k1, uint32_t ctr){
  uint32_t a, b; tf2x32(k0, k1, 0u, ctr, a, b);
  uint32_t bits = a ^ b;
  float f = __uint_as_float((bits >> 9) | 0x3F800000u) - 1.0f;
  if (f == 0.0f) f = 1.17549435e-38f;   // minval = tiny
  return -logf(-logf(f));
}

// ---------------- setup: fold x@Wih.T through W_embed ----------------
__global__ void setup_kernel(const float* __restrict__ We, const float* __restrict__ eWih,
                             const float* __restrict__ dWih, const float* __restrict__ dec0,
                             float* __restrict__ M3e, float* __restrict__ M3d, float* __restrict__ g0d){
  int id = blockIdx.x * 256 + threadIdx.x;
  if (id < 1536){
    int oo = id / 3, d = id % 3;
    double a = 0.0;
    for (int k = 0; k < 128; ++k) a += (double)eWih[oo*128+k] * (double)We[k*3+d];
    M3e[oo*4+d] = (float)a;
    if (d == 0) M3e[oo*4+3] = 0.f;
  } else if (id < 3072){
    int id2 = id - 1536; int oo = id2 / 3, d = id2 % 3;
    double a = 0.0;
    for (int k = 0; k < 128; ++k) a += (double)dWih[oo*128+k] * (double)We[k*3+d];
    M3d[oo*4+d] = (float)a;
    if (d == 0) M3d[oo*4+3] = 0.f;
  } else if (id < 3584){
    int oo = id - 3072;
    double a = 0.0;
    for (int k = 0; k < 128; ++k) a += (double)dWih[oo*128+k] * (double)dec0[k];
    g0d[oo] = (float)a;
  }
}

// ---------------- encoder: 256 blocks x 8 rows, 128 steps ----------------
__global__ __launch_bounds__(512, 2) void enc_kernel(
    const float* __restrict__ x, const float* __restrict__ Whh,
    const float* __restrict__ eb, const float* __restrict__ M3,
    float* __restrict__ ref, float* __restrict__ hcfin){
  __shared__ float pred[4][8][512];
  __shared__ float hT[128][8];
  __shared__ float cT[8][128];
  __shared__ float m3s[512][4];
  __shared__ float bs[512];
  __shared__ float xs[8][4];
  const int tid = threadIdx.x;
  const int lane = tid & 63;
  const int b0 = blockIdx.x << 3;

  { int i = tid; bs[i] = eb[i];
    float4 mv = *(const float4*)&M3[i*4]; *(float4*)&m3s[i][0] = mv; }
  for (int i = tid; i < 1024; i += 512){ ((float*)hT)[i] = 0.f; ((float*)cT)[i] = 0.f; }

  const int og = tid & 127, kp = tid >> 7;
  float w[4][32];
#pragma unroll
  for (int c = 0; c < 4; ++c)
#pragma unroll
    for (int i = 0; i < 32; i += 4){
      float4 v = *(const float4*)&Whh[(og*4+c)*128 + kp*32 + i];
      w[c][i] = v.x; w[c][i+1] = v.y; w[c][i+2] = v.z; w[c][i+3] = v.w;
    }
  __syncthreads();

#pragma unroll 1
  for (int t = 0; t < 128; ++t){
    if (tid < 32){ int r = tid >> 2, d = tid & 3;
      xs[r][d] = (d < 3) ? x[((b0+r)*128 + t)*3 + d] : 0.f; }
    float h8[8];
    { int krow = kp*32 + (lane & 31);
      float4 p0 = *(const float4*)&hT[krow][0];
      float4 p1 = *(const float4*)&hT[krow][4];
      h8[0]=p0.x; h8[1]=p0.y; h8[2]=p0.z; h8[3]=p0.w;
      h8[4]=p1.x; h8[5]=p1.y; h8[6]=p1.z; h8[7]=p1.w; }
    float acc[8][4];
#pragma unroll
    for (int r = 0; r < 8; ++r){ acc[r][0]=0.f; acc[r][1]=0.f; acc[r][2]=0.f; acc[r][3]=0.f; }
#pragma unroll
    for (int i = 0; i < 32; ++i){
#pragma unroll
      for (int r = 0; r < 8; ++r){
        float hv = __int_as_float(__builtin_amdgcn_readlane(__float_as_int(h8[r]), i));
        acc[r][0] = fmaf(hv, w[0][i], acc[r][0]);
        acc[r][1] = fmaf(hv, w[1][i], acc[r][1]);
        acc[r][2] = fmaf(hv, w[2][i], acc[r][2]);
        acc[r][3] = fmaf(hv, w[3][i], acc[r][3]);
      }
    }
#pragma unroll
    for (int r = 0; r < 8; ++r){
      float4 v = {acc[r][0], acc[r][1], acc[r][2], acc[r][3]};
      *(float4*)&pred[kp][r][og*4] = v;
    }
    __syncthreads();   // B1
    { const int u = tid & 127; const int r0v = (tid >> 7) * 2;
#pragma unroll
      for (int rr = r0v; rr < r0v + 2; ++rr){
        float g[4];
#pragma unroll
        for (int gi = 0; gi < 4; ++gi){
          int oo = u + (gi << 7);
          float hw = ((pred[0][rr][oo] + pred[1][rr][oo]) + pred[2][rr][oo]) + pred[3][rr][oo];
          float xw = fmaf(m3s[oo][2], xs[rr][2], fmaf(m3s[oo][1], xs[rr][1], m3s[oo][0]*xs[rr][0]));
          g[gi] = (xw + hw) + bs[oo];
        }
        float i_ = xsig(g[0]), f_ = xsig(g[1]), gg = xtanh(g[2]), o_ = xsig(g[3]);
        float a1 = keepf(f_ * cT[rr][u]);
        float a2 = keepf(i_ * gg);
        float cn = a1 + a2;
        float hn = o_ * xtanh(cn);
        cT[rr][u] = cn; hT[u][rr] = hn;
        ref[(((size_t)(b0+rr))*128 + t)*128 + u] = hn;
        if (t == 127){ hcfin[(b0+rr)*256 + u] = hn; hcfin[(b0+rr)*256 + 128 + u] = cn; }
      }
    }
    __syncthreads();   // B2
  }
}

// ---------------- decoder: 2048 blocks x 1 row, 128 steps ----------------
__global__ __launch_bounds__(512, 2) void dec_kernel(
    const float* __restrict__ x,
    const float* __restrict__ Whh, const float* __restrict__ db,
    const float* __restrict__ Wq, const float* __restrict__ bq,
    const float* __restrict__ Wq2, const float* __restrict__ bq2,
    const float* __restrict__ Wref, const float* __restrict__ bref,
    const float* __restrict__ Wref2, const float* __restrict__ bref2,
    const float* __restrict__ Vec, const float* __restrict__ Vec2,
    const float* __restrict__ M3, const float* __restrict__ g0,
    const float* __restrict__ ref, const float* __restrict__ hcfin,
    float* __restrict__ out){
  __shared__ float u2g[128][132];
  __shared__ float u2p[128][132];
  __shared__ float gbuf[512];
  __shared__ float qpart[16][128];
  __shared__ float hbuf[128], cbuf[128], u1b[128], u1pb[128], qbuf[128];
  __shared__ float scb[128], lpb[128], maskf[128], abuf[128];
  __shared__ float vecb[128], vec2b[128], bqb[128], bq2b[128];
  __shared__ uint32_t keyx[128], keyy[128];
  __shared__ float xrb[4];
  const int tid = threadIdx.x;
  const int lane = tid & 63;
  const int wv = tid >> 6;
  const int b = blockIdx.x;

  if (tid < 128){
    uint32_t a, bb; tf2x32(0u, 42u, 0u, (uint32_t)tid, a, bb);  // split(key(42),128) foldlike
    keyx[tid] = a; keyy[tid] = bb;
    hbuf[tid] = hcfin[b*256 + tid];
    cbuf[tid] = hcfin[b*256 + 128 + tid];
    maskf[tid] = 0.f;
    vecb[tid] = Vec[tid]; vec2b[tid] = Vec2[tid];
    bqb[tid] = bq[tid];   bq2b[tid] = bq2[tid];
  }
  // u2g/u2p prologue: u2X[t][j] = bias[j] + Wref[j,:] . ref[b,t,:]
  {
    const int j = tid & 127, m = (tid >> 7) & 1, th = tid >> 8;
    const float* W = m ? Wref2 : Wref;
    const float bj = m ? bref2[j] : bref[j];
    float wrow[128];
#pragma unroll
    for (int k = 0; k < 128; k += 4){ float4 v = *(const float4*)&W[j*128+k];
      wrow[k]=v.x; wrow[k+1]=v.y; wrow[k+2]=v.z; wrow[k+3]=v.w; }
    float* dst = m ? &u2p[0][0] : &u2g[0][0];
#pragma unroll 1
    for (int t = th*64; t < th*64 + 64; ++t){
      const float* rr = ref + (((size_t)b)*128 + t)*128;
      float a = 0.f;
#pragma unroll
      for (int k = 0; k < 128; ++k) a = fmaf(wrow[k], rr[k], a);
      dst[t*132 + j] = a + bj;
    }
  }
  // dec_Whh column into registers
  const int o = tid;
  float whh[128];
#pragma unroll
  for (int k = 0; k < 128; k += 4){ float4 v = *(const float4*)&Whh[o*128+k];
    whh[k]=v.x; whh[k+1]=v.y; whh[k+2]=v.z; whh[k+3]=v.w; }
  const float bo = db[o];
  float4 m4 = *(const float4*)&M3[o*4];
  const float g0o = g0[o];
  float llacc = 0.f;
  __syncthreads();

#pragma unroll 1
  for (int t = 0; t < 128; ++t){
    // ---- LSTM gates: g[o] = xw + h.Whh[o,:] + b[o]
    {
      float h0v = hbuf[lane], h1v = hbuf[64+lane];
      float acc = 0.f;
#pragma unroll
      for (int k = 0; k < 64; ++k){
        float hv = __int_as_float(__builtin_amdgcn_readlane(__float_as_int(h0v), k));
        acc = fmaf(hv, whh[k], acc);
      }
#pragma unroll
      for (int k = 0; k < 64; ++k){
        float hv = __int_as_float(__builtin_amdgcn_readlane(__float_as_int(h1v), k));
        acc = fmaf(hv, whh[64+k], acc);
      }
      float xw = (t == 0) ? g0o : fmaf(m4.z, xrb[2], fmaf(m4.y, xrb[1], m4.x*xrb[0]));
      gbuf[o] = (xw + acc) + bo;
    }
    __syncthreads(); // B1
    if (tid < 128){
      float gi = gbuf[tid], gf = gbuf[128+tid], gg = gbuf[256+tid], go = gbuf[384+tid];
      float i_ = xsig(gi), f_ = xsig(gf), g_ = xtanh(gg), o_ = xsig(go);
      float a1 = keepf(f_ * cbuf[tid]);
      float a2 = keepf(i_ * g_);
      float cn = a1 + a2;
      float hn = o_ * xtanh(cn);
      cbuf[tid] = cn; hbuf[tid] = hn;
    }
    __syncthreads(); // B2
    // ---- u1 = h @ Wq.T + bq
    {
      const int j = tid >> 2, kp = tid & 3;
      float a = 0.f;
#pragma unroll
      for (int i = 0; i < 32; i += 4){
        float4 wv = *(const float4*)&Wq[j*128 + kp*32 + i];
        float4 hv = *(const float4*)&hbuf[kp*32 + i];
        a = fmaf(wv.x,hv.x,a); a = fmaf(wv.y,hv.y,a); a = fmaf(wv.z,hv.z,a); a = fmaf(wv.w,hv.w,a);
      }
      a += __shfl_xor(a, 1);
      a += __shfl_xor(a, 2);
      if (kp == 0) u1b[j] = a + bqb[j];
    }
    __syncthreads(); // B3
    // ---- sc[n] = Vec . tanh(u1 + u2g[n]) - INF*mask
    {
      const int n = tid >> 2, hp = tid & 3;
      float s = 0.f;
#pragma unroll
      for (int i = 0; i < 32; i += 4){
        float4 ug = *(const float4*)&u2g[n][hp*32 + i];
        float4 uv = *(const float4*)&u1b[hp*32 + i];
        float4 vv = *(const float4*)&vecb[hp*32 + i];
        s = fmaf(xtanh(uv.x+ug.x), vv.x, s);
        s = fmaf(xtanh(uv.y+ug.y), vv.y, s);
        s = fmaf(xtanh(uv.z+ug.z), vv.z, s);
        s = fmaf(xtanh(uv.w+ug.w), vv.w, s);
      }
      s += __shfl_xor(s, 1);
      s += __shfl_xor(s, 2);
      if (hp == 0){ float mm = keepf(1e8f * maskf[n]); scb[n] = s - mm; }
    }
    __syncthreads(); // B4
    // ---- softmax over sc (each wave redundantly -> no barrier before q)
    {
      float v0 = scb[lane], v1 = scb[64+lane];
      float mx = fmaxf(v0, v1);
#pragma unroll
      for (int d2 = 1; d2 < 64; d2 <<= 1) mx = fmaxf(mx, __shfl_xor(mx, d2));
      float e0 = expf(v0 - mx), e1 = expf(v1 - mx);
      float sm = e0 + e1;
#pragma unroll
      for (int d2 = 1; d2 < 64; d2 <<= 1) sm += __shfl_xor(sm, d2);
      abuf[lane] = e0 / sm;
      abuf[64+lane] = e1 / sm;
    }
    // ---- q partials: q[h] = sum_n a[n] * u2g[n][h]
    {
      const int hc = tid & 31, np = tid >> 5;
      float q0=0.f,q1=0.f,q2=0.f,q3=0.f;
#pragma unroll
      for (int jj = 0; jj < 8; ++jj){
        int n = np*8 + jj;
        float an = abuf[n];
        float4 ug = *(const float4*)&u2g[n][hc*4];
        q0 = fmaf(an, ug.x, q0); q1 = fmaf(an, ug.y, q1);
        q2 = fmaf(an, ug.z, q2); q3 = fmaf(an, ug.w, q3);
      }
      float4 qv = {q0,q1,q2,q3};
      *(float4*)&qpart[np][hc*4] = qv;
    }
    __syncthreads(); // B5
    if (tid < 128){
      float s = qpart[0][tid];
#pragma unroll
      for (int np = 1; np < 16; ++np) s += qpart[np][tid];
      qbuf[tid] = s;
    }
    __syncthreads(); // B6
    // ---- u1p = q @ Wq2.T + bq2
    {
      const int j = tid >> 2, kp = tid & 3;
      float a = 0.f;
#pragma unroll
      for (int i = 0; i < 32; i += 4){
        float4 wv = *(const float4*)&Wq2[j*128 + kp*32 + i];
        float4 hv = *(const float4*)&qbuf[kp*32 + i];
        a = fmaf(wv.x,hv.x,a); a = fmaf(wv.y,hv.y,a); a = fmaf(wv.z,hv.z,a); a = fmaf(wv.w,hv.w,a);
      }
      a += __shfl_xor(a, 1);
      a += __shfl_xor(a, 2);
      if (kp == 0) u1pb[j] = a + bq2b[j];
    }
    __syncthreads(); // B7
    // ---- logits[n] = Vec2 . (10*tanh(u1p + u2p[n])) - INF*mask
    {
      const int n = tid >> 2, hp = tid & 3;
      float s = 0.f;
#pragma unroll
      for (int i = 0; i < 32; i += 4){
        float4 ug = *(const float4*)&u2p[n][hp*32 + i];
        float4 uv = *(const float4*)&u1pb[hp*32 + i];
        float4 vv = *(const float4*)&vec2b[hp*32 + i];
        s = fmaf(10.0f*xtanh(uv.x+ug.x), vv.x, s);
        s = fmaf(10.0f*xtanh(uv.y+ug.y), vv.y, s);
        s = fmaf(10.0f*xtanh(uv.z+ug.z), vv.z, s);
        s = fmaf(10.0f*xtanh(uv.w+ug.w), vv.w, s);
      }
      s += __shfl_xor(s, 1);
      s += __shfl_xor(s, 2);
      if (hp == 0){ float mm = keepf(1e8f * maskf[n]); scb[n] = s - mm; }
    }
    __syncthreads(); // B8
    // ---- log_softmax + gumbel argmax + bookkeeping (wave 0)
    if (wv == 0){
      float v0 = scb[lane], v1 = scb[64+lane];
      float mx = fmaxf(v0, v1);
#pragma unroll
      for (int d2 = 1; d2 < 64; d2 <<= 1) mx = fmaxf(mx, __shfl_xor(mx, d2));
      float s0 = v0 - mx, s1 = v1 - mx;
      float e0 = expf(s0), e1 = expf(s1);
      float sm = e0 + e1;
#pragma unroll
      for (int d2 = 1; d2 < 64; d2 <<= 1) sm += __shfl_xor(sm, d2);
      float lz = logf(sm);
      float lp0 = s0 - lz, lp1 = s1 - lz;
      lpb[lane] = lp0; lpb[64+lane] = lp1;
      float gv0 = gumbel_from(keyx[t], keyy[t], (uint32_t)(b*128 + lane));
      float gv1 = gumbel_from(keyx[t], keyy[t], (uint32_t)(b*128 + 64 + lane));
      float val0 = gv0 + lp0, val1 = gv1 + lp1;
      float bv; int bi;
      if (val1 > val0){ bv = val1; bi = 64 + lane; } else { bv = val0; bi = lane; }
#pragma unroll
      for (int d2 = 1; d2 < 64; d2 <<= 1){
        float ov = __shfl_xor(bv, d2);
        int   oi = __shfl_xor(bi, d2);
        if (ov > bv || (ov == bv && oi < bi)){ bv = ov; bi = oi; }
      }
      if (lane == 0){
        out[b*128 + t] = (float)bi;
        llacc += lpb[bi];
        maskf[bi] = 1.f;
      }
      if (lane < 3) xrb[lane] = x[((size_t)(b*128 + bi))*3 + lane];
    }
    __syncthreads(); // B9
  }
  if (tid == 0) out[262144 + b] = llacc;
}

// ---------------- launch ----------------
extern "C" void kernel_launch(void* const* d_in, const int* in_sizes, int n_in,
                              void* d_out, int out_size, void* d_ws, size_t ws_size,
                              hipStream_t stream){
  (void)in_sizes; (void)n_in; (void)out_size; (void)ws_size;
  const float* x        = (const float*)d_in[0];
  const float* W_embed  = (const float*)d_in[1];
  const float* enc_Wih  = (const float*)d_in[2];
  const float* enc_Whh  = (const float*)d_in[3];
  const float* enc_b    = (const float*)d_in[4];
  const float* dec_Wih  = (const float*)d_in[5];
  const float* dec_Whh  = (const float*)d_in[6];
  const float* dec_b    = (const float*)d_in[7];
  const float* Wq       = (const float*)d_in[8];
  const float* bq       = (const float*)d_in[9];
  const float* Wq2      = (const float*)d_in[10];
  const float* bq2      = (const float*)d_in[11];
  const float* Wref     = (const float*)d_in[12];
  const float* bref     = (const float*)d_in[13];
  const float* Wref2    = (const float*)d_in[14];
  const float* bref2    = (const float*)d_in[15];
  const float* Vec      = (const float*)d_in[16];
  const float* Vec2     = (const float*)d_in[17];
  const float* dec0     = (const float*)d_in[18];
  float* out = (float*)d_out;
  char* ws = (char*)d_ws;
  float* ref   = (float*)(ws);                       // 2048*128*128*4 = 134217728 B
  float* hcfin = (float*)(ws + 134217728);           // 2048*256*4    = 2097152 B
  float* M3e   = (float*)(ws + 136314880);           // 512*4*4 = 8192 B
  float* M3d   = (float*)(ws + 136323072);           // 8192 B
  float* g0d   = (float*)(ws + 136331264);           // 2048 B

  setup_kernel<<<14, 256, 0, stream>>>(W_embed, enc_Wih, dec_Wih, dec0, M3e, M3d, g0d);
  enc_kernel<<<256, 512, 0, stream>>>(x, enc_Whh, enc_b, M3e, ref, hcfin);
  dec_kernel<<<2048, 512, 0, stream>>>(x, dec_Whh, dec_b, Wq, bq, Wq2, bq2,
                                       Wref, bref, Wref2, bref2, Vec, Vec2,
                                       M3d, g0d, ref, hcfin, out);
}